// Round 13
// baseline (237.208 us; speedup 1.0000x reference)
//
#include <hip/hip_runtime.h>

// TemporalLogicLayer R26: revert to R22 3-kernel structure + HSTR2 152->156
// (hB bank-conflict halving). out[b,t,o]=max_s sigmoid(5*MLP(cummax|P)).
//
// R25 post-mortem: sigmoid-domain atomicMax fusion passed but FETCH 10->211MB,
// main 79->144us -- device-scope atomics at the cross-XCD coherence point
// destroy the L2 locality of the per-item weight working set. Reverted to the
// proven R22 structure (slots + finalize kernel, 152.1us).
//
// R26 change (constant-only): HSTR2 156. Old stride 304B = 76 dwords,
// 76%32=12, gcd(12,32)=4 -> a wave's 16 ln-rows hit 8 bank-start positions
// (8-way). New stride 312B = 78 dwords, 78%32=14, gcd(14,32)=2 -> 16 distinct
// bank-starts, ~2x fewer conflicts on every hB ds_read/ds_write.
// ZOFF_E=36352, SMEM_BYTES=72736 (2 blocks/CU preserved: 145.5KB<160KB).
// Everything else identical to R22 (64 VGPR; NBLK=512; setprio; 4 barriers).

#define TT 128
#define BB 32
#define DD 128
#define OO 64
#define NP 144
#define HSTR2 156
#define KSLOT 17
#define NBLK 512
#define H_OFFE 16384                                // f16 idx of hB (byte 32768)
#define ZOFF_E (H_OFFE + 128*HSTR2)                 // f16 idx 36352 (byte 72704)
#define SMEM_BYTES (2*ZOFF_E + 32)                  // 72736 B

typedef __attribute__((ext_vector_type(8))) _Float16 half8;
typedef __attribute__((ext_vector_type(4))) _Float16 half4;
typedef __attribute__((ext_vector_type(2))) __fp16 fp16x2;
typedef __attribute__((ext_vector_type(4))) float f32x4;

// ws layout (bytes)
#define W1T_OFF 0                                   // f16 [144][128] (K<128 half)
#define W2T_OFF (W1T_OFF + 144*128*2)               // f16 [144][160]
#define W3T_OFF (W2T_OFF + 144*160*2)               // f16 [64][160]
#define B1P_OFF (W3T_OFF + 64*160*2)                // f32 [144]
#define B2P_OFF (B1P_OFF + 144*4)                   // f32 [144]
#define PW_OFF  (B2P_OFF + 144*4)                   // f16 [4096][144]
#define PF_OFF  (PW_OFF + 4096*144*2)               // f16 [32][128][128]
#define SLOT_OFF (PF_OFF + 32*128*128*2)            // f16 [128][KSLOT][32][64]

#define MFMA(A, B, C) __builtin_amdgcn_mfma_f32_16x16x32_f16((A), (B), (C), 0, 0, 0)

__device__ __forceinline__ half8 h8max(half8 a, half8 b) {
    half8 r;
    #pragma unroll
    for (int i = 0; i < 8; ++i) r[i] = __builtin_fmaxf16(a[i], b[i]);
    return r;
}

// packed f32x4 -> half4 (RTZ)
__device__ __forceinline__ half4 cvt4(f32x4 v) {
    fp16x2 lo = __builtin_amdgcn_cvt_pkrtz(v[0], v[1]);
    fp16x2 hi = __builtin_amdgcn_cvt_pkrtz(v[2], v[3]);
    half4 r;
    r[0] = (_Float16)lo[0]; r[1] = (_Float16)lo[1];
    r[2] = (_Float16)hi[0]; r[3] = (_Float16)hi[1];
    return r;
}

// relu then packed convert
__device__ __forceinline__ half4 relu_cvt4(f32x4 v) {
    f32x4 t;
    #pragma unroll
    for (int i = 0; i < 4; ++i) t[i] = fmaxf(v[i], 0.f);
    return cvt4(t);
}

// largest bid with range_start(bid) = (bid*33)>>3 <= it   (512-block partition)
__device__ __forceinline__ int bid_of(int it) {
    int bb = (8 * it) / 33;
    while ((((bb + 1) * 33) >> 3) <= it) ++bb;
    while (((bb * 33) >> 3) > it) --bb;
    return bb;
}

// ---------- prep (240 blocks x 256) ----------
__global__ void tll_prep(const float* __restrict__ P,
                         const float* __restrict__ W1, const float* __restrict__ b1,
                         const float* __restrict__ W2, const float* __restrict__ b2,
                         const float* __restrict__ W3, char* __restrict__ ws) {
    __shared__ _Float16 w1s[144 * 130];             // 37440 B (PW blocks only)
    const int blk = blockIdx.x, tid = threadIdx.x;
    if (blk < 144) {
        _Float16* W1t = (_Float16*)(ws + W1T_OFF);
        _Float16* W2t = (_Float16*)(ws + W2T_OFF);
        _Float16* W3t = (_Float16*)(ws + W3T_OFF);
        float*    b1p = (float*)(ws + B1P_OFF);
        float*    b2p = (float*)(ws + B2P_OFF);
        int idx = blk * 256 + tid;
        if (idx < 144*128) {                        // W1t[n][k] = W1[k][n], k<128
            int n = idx >> 7, k = idx & 127;
            W1t[idx] = (_Float16)((n < 132) ? W1[k*132 + n] : 0.f);
        }
        if (idx < 144*160) {                        // W2t[n][k] = W2[k][n]
            int n = idx / 160, k = idx - n*160;
            W2t[idx] = (_Float16)((n < 132 && k < 132) ? W2[k*132 + n] : 0.f);
        }
        if (idx < 64*160) {                         // W3t[o][k] = W3[k][o]
            int o = idx / 160, k = idx - o*160;
            W3t[idx] = (_Float16)((k < 132) ? W3[k*64 + o] : 0.f);
        }
        if (idx < 144) {
            b1p[idx] = (idx < 132) ? b1[idx] : 0.f;
            b2p[idx] = (idx < 132) ? b2[idx] : 0.f;
        }
    } else if (blk < 208) {
        // PW[row][n] = P[row] @ W1[128:256, :], row = s*32+b (coalesced+LDS)
        _Float16* PW = (_Float16*)(ws + PW_OFF);
        const int blkp = blk - 144;
        for (int i = tid; i < 128*132; i += 256) {  // i: k-major, n consecutive
            int k = i / 132, n = i - k*132;
            w1s[n*130 + k] = (_Float16)W1[(128 + k)*132 + n];
        }
        for (int i = tid; i < 12*130; i += 256) {   // zero pad n = 132..143
            int n = 132 + i/130, k = i - (i/130)*130;
            w1s[n*130 + k] = (_Float16)0.f;
        }
        __syncthreads();
        const int w = tid >> 6, lane = tid & 63;
        const int ln = lane & 15, q = lane >> 4;
        const int row = (blkp*4 + w)*16 + ln;       // 0..4095
        const int b_ = row & 31, s_ = row >> 5;
        const float* pp = P + b_*(TT*DD) + s_*DD;
        half8 Bf[4];
        #pragma unroll
        for (int kst = 0; kst < 4; ++kst) {
            f32x4 p0 = *(const f32x4*)(pp + kst*32 + q*8);
            f32x4 p1 = *(const f32x4*)(pp + kst*32 + q*8 + 4);
            half8 h;
            #pragma unroll
            for (int i = 0; i < 4; ++i) { h[i] = (_Float16)p0[i]; h[4+i] = (_Float16)p1[i]; }
            Bf[kst] = h;
        }
        for (int mt = 0; mt < 9; ++mt) {
            f32x4 acc = (f32x4){0.f, 0.f, 0.f, 0.f};
            #pragma unroll
            for (int kst = 0; kst < 4; ++kst) {
                half8 A = *(const half8*)&w1s[(mt*16 + ln)*130 + kst*32 + q*8];
                acc = MFMA(A, Bf[kst], acc);
            }
            half4 hv;
            #pragma unroll
            for (int i = 0; i < 4; ++i) hv[i] = (_Float16)acc[i];
            *(half4*)(PW + (size_t)row*NP + mt*16 + q*4) = hv;
        }
    } else {
        // Pf[b] = f16(P[b])
        _Float16* Pf = (_Float16*)(ws + PF_OFF);
        const int b = blk - 208;
        const f32x4* src = (const f32x4*)(P + (size_t)b * TT * DD);
        half4* dst = (half4*)(Pf + (size_t)b * TT * DD);
        for (int i = tid; i < TT*DD/4; i += 256) {
            f32x4 v = src[i];
            half4 h;
            #pragma unroll
            for (int j = 0; j < 4; ++j) h[j] = (_Float16)v[j];
            dst[i] = h;
        }
    }
}

// ---------- finalize (128 blocks x 512): out = sigmoid(5 * max_k slots) ----------
__global__ void tll_finalize(const char* __restrict__ ws, float* __restrict__ out) {
    const int t = blockIdx.x, tid = threadIdx.x;
    const int g = t >> 2;
    const int it_s = 2*g*(65 - g) + (t - 4*g)*(32 - g);
    const int it_e = it_s + (32 - g);
    const int n = bid_of(it_e - 1) - bid_of(it_s) + 1;     // <= 9 (< KSLOT)
    const _Float16* slots = (const _Float16*)(ws + SLOT_OFF) + (size_t)t * KSLOT * 2048;
    const int cell = tid * 4;                              // 2048 cells: b*64+o
    half4 h = *(const half4*)(slots + cell);
    f32x4 v;
    #pragma unroll
    for (int i = 0; i < 4; ++i) v[i] = (float)h[i];
    for (int k = 1; k < n; ++k) {
        half4 u = *(const half4*)(slots + k*2048 + cell);
        #pragma unroll
        for (int i = 0; i < 4; ++i) v[i] = fmaxf(v[i], (float)u[i]);
    }
    f32x4 y;
    #pragma unroll
    for (int i = 0; i < 4; ++i) y[i] = 1.f / (1.f + __expf(-5.f * v[i]));
    const int b = cell >> 6, o = cell & 63;
    *(f32x4*)(out + (size_t)b*(TT*OO) + t*OO + o) = y;
}

// ---------- main ----------
__global__ __launch_bounds__(512, 4) void tll_main(
    const float* __restrict__ b3, char* __restrict__ ws)
{
    // LDS: cmx and hB separate; scr overlays cmx (dead during flush).
    __shared__ __attribute__((aligned(16))) char smem[SMEM_BYTES];
    _Float16* cmx = (_Float16*)smem;                 // [128][128] swizzled, 32KB
    _Float16* hB  = (_Float16*)smem + H_OFFE;        // [128][156]
    const _Float16* zstrip = (const _Float16*)smem + ZOFF_E;   // 32 B zeros
    float* scr = (float*)smem;                       // flush scratch over cmx

    const _Float16* W1t = (const _Float16*)(ws + W1T_OFF);
    const _Float16* W2t = (const _Float16*)(ws + W2T_OFF);
    const _Float16* W3t = (const _Float16*)(ws + W3T_OFF);
    const float*    b1p = (const float*)(ws + B1P_OFF);
    const float*    b2p = (const float*)(ws + B2P_OFF);
    const _Float16* PW  = (const _Float16*)(ws + PW_OFF);
    const _Float16* Pf  = (const _Float16*)(ws + PF_OFF);
    _Float16*       slots = (_Float16*)(ws + SLOT_OFF);

    const int tid = threadIdx.x, w = tid >> 6, lane = tid & 63;
    const int ln = lane & 15, q = lane >> 4;
    const int fw0 = w*16;                           // this wave's f-tile cols
    const int og = w >> 1, rg3 = w & 1;             // L3 + flush roles (as R11)

    if (tid < 16) ((_Float16*)smem)[ZOFF_E + tid] = (_Float16)0.f;

    const int sb = tid >> 4, dblk = tid & 15, d0 = dblk*8;  // staging role
    const _Float16* pfb = Pf + (size_t)sb*(TT*DD) + d0;

    const int bid = blockIdx.x;
    int it = (bid*33) >> 3;                          // contiguous t-major ranges
    const int hi = ((bid + 1)*33) >> 3;

    int cur_t = -1;
    f32x4 rz0 = (f32x4){-1e30f,-1e30f,-1e30f,-1e30f};  // z-domain max, b=ln
    f32x4 rz1 = rz0;                                    // b=16+ln
    half8 mi;                                           // carried cummax Pf[b,t..s0-1,d]
    __syncthreads();

    for (; it < hi; ++it) {
        // ---- decode item -> (t, c) ----
        int g = (int)((65.0f - sqrtf((float)(4225 - 2*it))) * 0.5f);
        if (g < 0) g = 0; if (g > 31) g = 31;
        while (g > 0 && 2*g*(65 - g) > it) --g;
        while (2*(g+1)*(65 - (g+1)) <= it) ++g;
        int rem = it - 2*g*(65 - g);
        int ntc = 32 - g;
        int t  = 4*g + rem/ntc;
        int c  = rem - (rem/ntc)*ntc;
        int s0 = t + 4*c;

        // ---- PW loads for THIS item's L1, hoisted to iteration top ----
        half4 pw[8]; half4 pwS;
        #pragma unroll
        for (int rt = 0; rt < 8; ++rt) {
            int row = rt*16 + ln;
            int sj = s0 + (row >> 5); if (sj > 127) sj = 127;
            int rowg = sj*32 + (row & 31);
            pw[rt] = *(const half4*)(PW + (size_t)rowg*NP + fw0 + q*4);
            if (rt == w) pwS = *(const half4*)(PW + (size_t)rowg*NP + 128 + q*4);
        }

        // ---- t-change: flush z-max to slot, reset + scan-init carry ----
        if (t != cur_t) {                            // block-uniform branch
            if (cur_t >= 0) {
                // scr = cmx region; all cmx reads done by barrier [B] of the
                // previous item; L3 stragglers only touch hB (disjoint).
                if (rg3 == 1) {
                    *(f32x4*)(scr + (og*64 + lane)*8)     = rz0;
                    *(f32x4*)(scr + (og*64 + lane)*8 + 4) = rz1;
                }
                __syncthreads();
                if (rg3 == 0) {
                    f32x4 p0 = *(const f32x4*)(scr + (og*64 + lane)*8);
                    f32x4 p1 = *(const f32x4*)(scr + (og*64 + lane)*8 + 4);
                    #pragma unroll
                    for (int i = 0; i < 4; ++i) {
                        rz0[i] = fmaxf(rz0[i], p0[i]);
                        rz1[i] = fmaxf(rz1[i], p1[i]);
                    }
                    int k = bid - bid_of(2*(cur_t >> 2)*(65 - (cur_t >> 2))
                                         + (cur_t - 4*(cur_t >> 2))*(32 - (cur_t >> 2)));
                    _Float16* sp = slots + ((size_t)cur_t*KSLOT + k)*2048;
                    int o = og*16 + q*4;
                    half4 z0 = cvt4(rz0), z1 = cvt4(rz1);
                    __builtin_nontemporal_store(z0, (half4*)(sp + ln*64 + o));
                    __builtin_nontemporal_store(z1, (half4*)(sp + (16+ln)*64 + o));
                }
                __syncthreads();                     // protect scr before staging
            }
            cur_t = t;
            rz0 = (f32x4){-1e30f,-1e30f,-1e30f,-1e30f};
            rz1 = rz0;
            half8 m1;
            #pragma unroll
            for (int i = 0; i < 8; ++i) { mi[i] = (_Float16)(-65504.0f); m1[i] = (_Float16)(-65504.0f); }
            {                                        // 2-acc scan (max associative)
                int s = t;
                for (; s + 1 < s0; s += 2) {
                    mi = h8max(mi, *(const half8*)(pfb + s*DD));
                    m1 = h8max(m1, *(const half8*)(pfb + (s+1)*DD));
                }
                if (s < s0) mi = h8max(mi, *(const half8*)(pfb + s*DD));
                mi = h8max(mi, m1);
            }
        }

        // ---- stage cmx: fold 4 steps onto carried mi ----
        #pragma unroll
        for (int j = 0; j < 4; ++j) {
            int s = s0 + j; if (s > 127) s = 127;    // dup of valid s=127, same b
            mi = h8max(mi, *(const half8*)(pfb + s*DD));
            int row = j*32 + sb;
            *(half8*)(cmx + row*128 + ((dblk ^ (row & 15))*8)) = mi;
        }
        __syncthreads();                             // [A]

        // ---- L1': balanced — wave w: f-tile w x 8 row-tiles + S-unit(rt=w) ----
        f32x4 acc[8], accS;
        {
            const f32x4 b1w = *(const f32x4*)(b1p + fw0 + q*4);
            const f32x4 b1S = *(const f32x4*)(b1p + 128 + q*4);
            #pragma unroll
            for (int rt = 0; rt < 8; ++rt) {
                acc[rt] = b1w;
                #pragma unroll
                for (int i = 0; i < 4; ++i) acc[rt][i] += (float)pw[rt][i];
            }
            accS = b1S;
            #pragma unroll
            for (int i = 0; i < 4; ++i) accS[i] += (float)pwS[i];
            __builtin_amdgcn_s_setprio(1);
            #pragma unroll
            for (int kst = 0; kst < 4; ++kst) {
                half8 wA = *(const half8*)(W1t + (fw0+ln)*128 + kst*32 + q*8);
                half8 wS = *(const half8*)(W1t + (128+ln)*128 + kst*32 + q*8);
                int kb = kst*4 + q;
                #pragma unroll
                for (int rt = 0; rt < 8; ++rt) {
                    int row = rt*16 + ln;                // row & 15 == ln
                    half8 bf = *(const half8*)(cmx + row*128 + ((kb ^ ln)*8));
                    acc[rt] = MFMA(wA, bf, acc[rt]);
                    if (rt == w) accS = MFMA(wS, bf, accS);
                }
            }
            __builtin_amdgcn_s_setprio(0);
        }
        // [A2] removed: h1 writes target hB, disjoint from cmx reads.
        #pragma unroll
        for (int rt = 0; rt < 8; ++rt) {             // relu -> h1 over hB
            int row = rt*16 + ln;
            *(half4*)(hB + row*HSTR2 + fw0 + q*4) = relu_cvt4(acc[rt]);
        }
        *(half4*)(hB + (w*16 + ln)*HSTR2 + 128 + q*4) = relu_cvt4(accS);
        __syncthreads();                             // [B]

        // ---- L2': same balanced split, K=160 (zstrip covers cols 144..159) ----
        half4 h2[8], h2S;
        {
            const f32x4 b2w = *(const f32x4*)(b2p + fw0 + q*4);
            const f32x4 b2S = *(const f32x4*)(b2p + 128 + q*4);
            #pragma unroll
            for (int rt = 0; rt < 8; ++rt) acc[rt] = b2w;
            accS = b2S;
            __builtin_amdgcn_s_setprio(1);
            #pragma unroll
            for (int kst = 0; kst < 5; ++kst) {
                half8 wA = *(const half8*)(W2t + (fw0+ln)*160 + kst*32 + q*8);
                half8 wS = *(const half8*)(W2t + (128+ln)*160 + kst*32 + q*8);
                #pragma unroll
                for (int rt = 0; rt < 8; ++rt) {
                    int row = rt*16 + ln;
                    half8 bf = (kst < 4)
                        ? *(const half8*)(hB + row*HSTR2 + kst*32 + q*8)
                        : ((q < 2) ? *(const half8*)(hB + row*HSTR2 + 128 + q*8)
                                   : *(const half8*)zstrip);
                    acc[rt] = MFMA(wA, bf, acc[rt]);
                    if (rt == w) accS = MFMA(wS, bf, accS);
                }
            }
            __builtin_amdgcn_s_setprio(0);
            #pragma unroll
            for (int rt = 0; rt < 8; ++rt) h2[rt] = relu_cvt4(acc[rt]);
            h2S = relu_cvt4(accS);
        }
        __syncthreads();                             // [C] all h1 reads done
        #pragma unroll
        for (int rt = 0; rt < 8; ++rt) {
            int row = rt*16 + ln;
            *(half4*)(hB + row*HSTR2 + fw0 + q*4) = h2[rt];
        }
        *(half4*)(hB + (w*16 + ln)*HSTR2 + 128 + q*4) = h2S;
        __syncthreads();                             // [D]

        // ---- L3': z3^T = W3^T @ h2^T (4 o-tiles x 2 row-halves, balanced) ----
        {
            const f32x4 bz3 = *(const f32x4*)(b3 + og*16 + q*4);
            f32x4 z[4];
            #pragma unroll
            for (int rj = 0; rj < 4; ++rj) z[rj] = bz3;
            __builtin_amdgcn_s_setprio(1);
            #pragma unroll
            for (int kst = 0; kst < 5; ++kst) {
                half8 wO = *(const half8*)(W3t + (og*16+ln)*160 + kst*32 + q*8);
                #pragma unroll
                for (int rj = 0; rj < 4; ++rj) {
                    int row = (rg3*4 + rj)*16 + ln;
                    half8 bf = (kst < 4)
                        ? *(const half8*)(hB + row*HSTR2 + kst*32 + q*8)
                        : ((q < 2) ? *(const half8*)(hB + row*HSTR2 + 128 + q*8)
                                   : *(const half8*)zstrip);
                    z[rj] = MFMA(wO, bf, z[rj]);
                }
            }
            __builtin_amdgcn_s_setprio(0);
            // rows encode (j = rg3*2 + (rj>>1), b = (rj&1)*16 + ln); clamped
            // rows duplicate (s=127, same b) -> merge all unconditionally
            #pragma unroll
            for (int i = 0; i < 4; ++i) {
                rz0[i] = fmaxf(rz0[i], fmaxf(z[0][i], z[2][i]));
                rz1[i] = fmaxf(rz1[i], fmaxf(z[1][i], z[3][i]));
            }
        }
        // [E] removed: next item's staging writes cmx; L3 reads hB (disjoint).
    }

    // ---- final flush ----
    {
        if (rg3 == 1) {
            *(f32x4*)(scr + (og*64 + lane)*8)     = rz0;
            *(f32x4*)(scr + (og*64 + lane)*8 + 4) = rz1;
        }
        __syncthreads();
        if (rg3 == 0) {
            f32x4 p0 = *(const f32x4*)(scr + (og*64 + lane)*8);
            f32x4 p1 = *(const f32x4*)(scr + (og*64 + lane)*8 + 4);
            #pragma unroll
            for (int i = 0; i < 4; ++i) {
                rz0[i] = fmaxf(rz0[i], p0[i]);
                rz1[i] = fmaxf(rz1[i], p1[i]);
            }
            int k = bid - bid_of(2*(cur_t >> 2)*(65 - (cur_t >> 2))
                                 + (cur_t - 4*(cur_t >> 2))*(32 - (cur_t >> 2)));
            _Float16* sp = slots + ((size_t)cur_t*KSLOT + k)*2048;
            int o = og*16 + q*4;
            half4 z0 = cvt4(rz0), z1 = cvt4(rz1);
            __builtin_nontemporal_store(z0, (half4*)(sp + ln*64 + o));
            __builtin_nontemporal_store(z1, (half4*)(sp + (16+ln)*64 + o));
        }
    }
}

extern "C" void kernel_launch(void* const* d_in, const int* in_sizes, int n_in,
                              void* d_out, int out_size, void* d_ws, size_t ws_size,
                              hipStream_t stream) {
    const float* P  = (const float*)d_in[0];
    const float* W1 = (const float*)d_in[1];
    const float* b1 = (const float*)d_in[2];
    const float* W2 = (const float*)d_in[3];
    const float* b2 = (const float*)d_in[4];
    const float* W3 = (const float*)d_in[5];
    const float* b3 = (const float*)d_in[6];

    tll_prep<<<240, 256, 0, stream>>>(P, W1, b1, W2, b2, W3, (char*)d_ws);

    tll_main<<<NBLK, 512, 0, stream>>>(b3, (char*)d_ws);

    tll_finalize<<<128, 512, 0, stream>>>((const char*)d_ws, (float*)d_out);
}

// Round 15
// 151.940 us; speedup vs baseline: 1.5612x; 1.5612x over previous
//
#include <hip/hip_runtime.h>

// TemporalLogicLayer R28: resubmit of R27 (== R22, session best: 152.1us
// total, main 79.4us). Round-14 bench was an infra failure (container died
// twice) -- no kernel signal; source unchanged.
// out[b,t,o] = max_{s>=t} sigmoid(5*MLP([cummax(P[t..s])|P[s]])).
//
// Ledger (all counter-verified this session):
//  kept: VALU diet (fmaxf16/cvt_pkrtz), PW hoist, de-overlaid LDS (4
//        barriers/item), NBLK=512 full co-residency (2 blocks/CU, the -32us
//        lever), s_setprio on MFMA clusters. 64 VGPR.
//  closed: register caching (>64-VGPR builds fail in this env:
//        R14/R15/R23/R24), atomic out-fusion (FETCH 10->211MB, R25),
//        stride-based conflict fix (alignment-bound + conflicts off the
//        critical path, R26), NBLK=1024 (prologue-dominated, R20/R21),
//        threadfence fusion (prior session R12).

#define TT 128
#define BB 32
#define DD 128
#define OO 64
#define NP 144
#define HSTR2 152
#define KSLOT 17
#define NBLK 512
#define SMEM_BYTES 71712
#define H_OFFE 16384                                // f16 idx of hB (byte 32768)
#define ZOFF_E (H_OFFE + 128*HSTR2)                 // f16 idx 35840 (byte 71680)

typedef __attribute__((ext_vector_type(8))) _Float16 half8;
typedef __attribute__((ext_vector_type(4))) _Float16 half4;
typedef __attribute__((ext_vector_type(2))) __fp16 fp16x2;
typedef __attribute__((ext_vector_type(4))) float f32x4;

// ws layout (bytes)
#define W1T_OFF 0                                   // f16 [144][128] (K<128 half)
#define W2T_OFF (W1T_OFF + 144*128*2)               // f16 [144][160]
#define W3T_OFF (W2T_OFF + 144*160*2)               // f16 [64][160]
#define B1P_OFF (W3T_OFF + 64*160*2)                // f32 [144]
#define B2P_OFF (B1P_OFF + 144*4)                   // f32 [144]
#define PW_OFF  (B2P_OFF + 144*4)                   // f16 [4096][144]
#define PF_OFF  (PW_OFF + 4096*144*2)               // f16 [32][128][128]
#define SLOT_OFF (PF_OFF + 32*128*128*2)            // f16 [128][KSLOT][32][64]

#define MFMA(A, B, C) __builtin_amdgcn_mfma_f32_16x16x32_f16((A), (B), (C), 0, 0, 0)

__device__ __forceinline__ half8 h8max(half8 a, half8 b) {
    half8 r;
    #pragma unroll
    for (int i = 0; i < 8; ++i) r[i] = __builtin_fmaxf16(a[i], b[i]);
    return r;
}

// packed f32x4 -> half4 (RTZ)
__device__ __forceinline__ half4 cvt4(f32x4 v) {
    fp16x2 lo = __builtin_amdgcn_cvt_pkrtz(v[0], v[1]);
    fp16x2 hi = __builtin_amdgcn_cvt_pkrtz(v[2], v[3]);
    half4 r;
    r[0] = (_Float16)lo[0]; r[1] = (_Float16)lo[1];
    r[2] = (_Float16)hi[0]; r[3] = (_Float16)hi[1];
    return r;
}

// relu then packed convert
__device__ __forceinline__ half4 relu_cvt4(f32x4 v) {
    f32x4 t;
    #pragma unroll
    for (int i = 0; i < 4; ++i) t[i] = fmaxf(v[i], 0.f);
    return cvt4(t);
}

// largest bid with range_start(bid) = (bid*33)>>3 <= it   (512-block partition)
__device__ __forceinline__ int bid_of(int it) {
    int bb = (8 * it) / 33;
    while ((((bb + 1) * 33) >> 3) <= it) ++bb;
    while (((bb * 33) >> 3) > it) --bb;
    return bb;
}

// ---------- prep (240 blocks x 256) ----------
__global__ void tll_prep(const float* __restrict__ P,
                         const float* __restrict__ W1, const float* __restrict__ b1,
                         const float* __restrict__ W2, const float* __restrict__ b2,
                         const float* __restrict__ W3, char* __restrict__ ws) {
    __shared__ _Float16 w1s[144 * 130];             // 37440 B (PW blocks only)
    const int blk = blockIdx.x, tid = threadIdx.x;
    if (blk < 144) {
        _Float16* W1t = (_Float16*)(ws + W1T_OFF);
        _Float16* W2t = (_Float16*)(ws + W2T_OFF);
        _Float16* W3t = (_Float16*)(ws + W3T_OFF);
        float*    b1p = (float*)(ws + B1P_OFF);
        float*    b2p = (float*)(ws + B2P_OFF);
        int idx = blk * 256 + tid;
        if (idx < 144*128) {                        // W1t[n][k] = W1[k][n], k<128
            int n = idx >> 7, k = idx & 127;
            W1t[idx] = (_Float16)((n < 132) ? W1[k*132 + n] : 0.f);
        }
        if (idx < 144*160) {                        // W2t[n][k] = W2[k][n]
            int n = idx / 160, k = idx - n*160;
            W2t[idx] = (_Float16)((n < 132 && k < 132) ? W2[k*132 + n] : 0.f);
        }
        if (idx < 64*160) {                         // W3t[o][k] = W3[k][o]
            int o = idx / 160, k = idx - o*160;
            W3t[idx] = (_Float16)((k < 132) ? W3[k*64 + o] : 0.f);
        }
        if (idx < 144) {
            b1p[idx] = (idx < 132) ? b1[idx] : 0.f;
            b2p[idx] = (idx < 132) ? b2[idx] : 0.f;
        }
    } else if (blk < 208) {
        // PW[row][n] = P[row] @ W1[128:256, :], row = s*32+b (coalesced+LDS)
        _Float16* PW = (_Float16*)(ws + PW_OFF);
        const int blkp = blk - 144;
        for (int i = tid; i < 128*132; i += 256) {  // i: k-major, n consecutive
            int k = i / 132, n = i - k*132;
            w1s[n*130 + k] = (_Float16)W1[(128 + k)*132 + n];
        }
        for (int i = tid; i < 12*130; i += 256) {   // zero pad n = 132..143
            int n = 132 + i/130, k = i - (i/130)*130;
            w1s[n*130 + k] = (_Float16)0.f;
        }
        __syncthreads();
        const int w = tid >> 6, lane = tid & 63;
        const int ln = lane & 15, q = lane >> 4;
        const int row = (blkp*4 + w)*16 + ln;       // 0..4095
        const int b_ = row & 31, s_ = row >> 5;
        const float* pp = P + b_*(TT*DD) + s_*DD;
        half8 Bf[4];
        #pragma unroll
        for (int kst = 0; kst < 4; ++kst) {
            f32x4 p0 = *(const f32x4*)(pp + kst*32 + q*8);
            f32x4 p1 = *(const f32x4*)(pp + kst*32 + q*8 + 4);
            half8 h;
            #pragma unroll
            for (int i = 0; i < 4; ++i) { h[i] = (_Float16)p0[i]; h[4+i] = (_Float16)p1[i]; }
            Bf[kst] = h;
        }
        for (int mt = 0; mt < 9; ++mt) {
            f32x4 acc = (f32x4){0.f, 0.f, 0.f, 0.f};
            #pragma unroll
            for (int kst = 0; kst < 4; ++kst) {
                half8 A = *(const half8*)&w1s[(mt*16 + ln)*130 + kst*32 + q*8];
                acc = MFMA(A, Bf[kst], acc);
            }
            half4 hv;
            #pragma unroll
            for (int i = 0; i < 4; ++i) hv[i] = (_Float16)acc[i];
            *(half4*)(PW + (size_t)row*NP + mt*16 + q*4) = hv;
        }
    } else {
        // Pf[b] = f16(P[b])
        _Float16* Pf = (_Float16*)(ws + PF_OFF);
        const int b = blk - 208;
        const f32x4* src = (const f32x4*)(P + (size_t)b * TT * DD);
        half4* dst = (half4*)(Pf + (size_t)b * TT * DD);
        for (int i = tid; i < TT*DD/4; i += 256) {
            f32x4 v = src[i];
            half4 h;
            #pragma unroll
            for (int j = 0; j < 4; ++j) h[j] = (_Float16)v[j];
            dst[i] = h;
        }
    }
}

// ---------- finalize (128 blocks x 512): out = sigmoid(5 * max_k slots) ----------
__global__ void tll_finalize(const char* __restrict__ ws, float* __restrict__ out) {
    const int t = blockIdx.x, tid = threadIdx.x;
    const int g = t >> 2;
    const int it_s = 2*g*(65 - g) + (t - 4*g)*(32 - g);
    const int it_e = it_s + (32 - g);
    const int n = bid_of(it_e - 1) - bid_of(it_s) + 1;     // <= 9 (< KSLOT)
    const _Float16* slots = (const _Float16*)(ws + SLOT_OFF) + (size_t)t * KSLOT * 2048;
    const int cell = tid * 4;                              // 2048 cells: b*64+o
    half4 h = *(const half4*)(slots + cell);
    f32x4 v;
    #pragma unroll
    for (int i = 0; i < 4; ++i) v[i] = (float)h[i];
    for (int k = 1; k < n; ++k) {
        half4 u = *(const half4*)(slots + k*2048 + cell);
        #pragma unroll
        for (int i = 0; i < 4; ++i) v[i] = fmaxf(v[i], (float)u[i]);
    }
    f32x4 y;
    #pragma unroll
    for (int i = 0; i < 4; ++i) y[i] = 1.f / (1.f + __expf(-5.f * v[i]));
    const int b = cell >> 6, o = cell & 63;
    *(f32x4*)(out + (size_t)b*(TT*OO) + t*OO + o) = y;
}

// ---------- main ----------
__global__ __launch_bounds__(512, 4) void tll_main(
    const float* __restrict__ b3, char* __restrict__ ws)
{
    // LDS: cmx and hB separate; scr overlays cmx (dead during flush).
    __shared__ __attribute__((aligned(16))) char smem[SMEM_BYTES];
    _Float16* cmx = (_Float16*)smem;                 // [128][128] swizzled, 32KB
    _Float16* hB  = (_Float16*)smem + H_OFFE;        // [128][152]
    const _Float16* zstrip = (const _Float16*)smem + ZOFF_E;   // 32 B zeros
    float* scr = (float*)smem;                       // flush scratch over cmx

    const _Float16* W1t = (const _Float16*)(ws + W1T_OFF);
    const _Float16* W2t = (const _Float16*)(ws + W2T_OFF);
    const _Float16* W3t = (const _Float16*)(ws + W3T_OFF);
    const float*    b1p = (const float*)(ws + B1P_OFF);
    const float*    b2p = (const float*)(ws + B2P_OFF);
    const _Float16* PW  = (const _Float16*)(ws + PW_OFF);
    const _Float16* Pf  = (const _Float16*)(ws + PF_OFF);
    _Float16*       slots = (_Float16*)(ws + SLOT_OFF);

    const int tid = threadIdx.x, w = tid >> 6, lane = tid & 63;
    const int ln = lane & 15, q = lane >> 4;
    const int fw0 = w*16;                           // this wave's f-tile cols
    const int og = w >> 1, rg3 = w & 1;             // L3 + flush roles (as R11)

    if (tid < 16) ((_Float16*)smem)[ZOFF_E + tid] = (_Float16)0.f;

    const int sb = tid >> 4, dblk = tid & 15, d0 = dblk*8;  // staging role
    const _Float16* pfb = Pf + (size_t)sb*(TT*DD) + d0;

    const int bid = blockIdx.x;
    int it = (bid*33) >> 3;                          // contiguous t-major ranges
    const int hi = ((bid + 1)*33) >> 3;

    int cur_t = -1;
    f32x4 rz0 = (f32x4){-1e30f,-1e30f,-1e30f,-1e30f};  // z-domain max, b=ln
    f32x4 rz1 = rz0;                                    // b=16+ln
    half8 mi;                                           // carried cummax Pf[b,t..s0-1,d]
    __syncthreads();

    for (; it < hi; ++it) {
        // ---- decode item -> (t, c) ----
        int g = (int)((65.0f - sqrtf((float)(4225 - 2*it))) * 0.5f);
        if (g < 0) g = 0; if (g > 31) g = 31;
        while (g > 0 && 2*g*(65 - g) > it) --g;
        while (2*(g+1)*(65 - (g+1)) <= it) ++g;
        int rem = it - 2*g*(65 - g);
        int ntc = 32 - g;
        int t  = 4*g + rem/ntc;
        int c  = rem - (rem/ntc)*ntc;
        int s0 = t + 4*c;

        // ---- PW loads for THIS item's L1, hoisted to iteration top ----
        half4 pw[8]; half4 pwS;
        #pragma unroll
        for (int rt = 0; rt < 8; ++rt) {
            int row = rt*16 + ln;
            int sj = s0 + (row >> 5); if (sj > 127) sj = 127;
            int rowg = sj*32 + (row & 31);
            pw[rt] = *(const half4*)(PW + (size_t)rowg*NP + fw0 + q*4);
            if (rt == w) pwS = *(const half4*)(PW + (size_t)rowg*NP + 128 + q*4);
        }

        // ---- t-change: flush z-max to slot, reset + scan-init carry ----
        if (t != cur_t) {                            // block-uniform branch
            if (cur_t >= 0) {
                // scr = cmx region; all cmx reads done by barrier [B] of the
                // previous item; L3 stragglers only touch hB (disjoint).
                if (rg3 == 1) {
                    *(f32x4*)(scr + (og*64 + lane)*8)     = rz0;
                    *(f32x4*)(scr + (og*64 + lane)*8 + 4) = rz1;
                }
                __syncthreads();
                if (rg3 == 0) {
                    f32x4 p0 = *(const f32x4*)(scr + (og*64 + lane)*8);
                    f32x4 p1 = *(const f32x4*)(scr + (og*64 + lane)*8 + 4);
                    #pragma unroll
                    for (int i = 0; i < 4; ++i) {
                        rz0[i] = fmaxf(rz0[i], p0[i]);
                        rz1[i] = fmaxf(rz1[i], p1[i]);
                    }
                    int k = bid - bid_of(2*(cur_t >> 2)*(65 - (cur_t >> 2))
                                         + (cur_t - 4*(cur_t >> 2))*(32 - (cur_t >> 2)));
                    _Float16* sp = slots + ((size_t)cur_t*KSLOT + k)*2048;
                    int o = og*16 + q*4;
                    half4 z0 = cvt4(rz0), z1 = cvt4(rz1);
                    __builtin_nontemporal_store(z0, (half4*)(sp + ln*64 + o));
                    __builtin_nontemporal_store(z1, (half4*)(sp + (16+ln)*64 + o));
                }
                __syncthreads();                     // protect scr before staging
            }
            cur_t = t;
            rz0 = (f32x4){-1e30f,-1e30f,-1e30f,-1e30f};
            rz1 = rz0;
            half8 m1;
            #pragma unroll
            for (int i = 0; i < 8; ++i) { mi[i] = (_Float16)(-65504.0f); m1[i] = (_Float16)(-65504.0f); }
            {                                        // 2-acc scan (max associative)
                int s = t;
                for (; s + 1 < s0; s += 2) {
                    mi = h8max(mi, *(const half8*)(pfb + s*DD));
                    m1 = h8max(m1, *(const half8*)(pfb + (s+1)*DD));
                }
                if (s < s0) mi = h8max(mi, *(const half8*)(pfb + s*DD));
                mi = h8max(mi, m1);
            }
        }

        // ---- stage cmx: fold 4 steps onto carried mi ----
        #pragma unroll
        for (int j = 0; j < 4; ++j) {
            int s = s0 + j; if (s > 127) s = 127;    // dup of valid s=127, same b
            mi = h8max(mi, *(const half8*)(pfb + s*DD));
            int row = j*32 + sb;
            *(half8*)(cmx + row*128 + ((dblk ^ (row & 15))*8)) = mi;
        }
        __syncthreads();                             // [A]

        // ---- L1': balanced — wave w: f-tile w x 8 row-tiles + S-unit(rt=w) ----
        f32x4 acc[8], accS;
        {
            const f32x4 b1w = *(const f32x4*)(b1p + fw0 + q*4);
            const f32x4 b1S = *(const f32x4*)(b1p + 128 + q*4);
            #pragma unroll
            for (int rt = 0; rt < 8; ++rt) {
                acc[rt] = b1w;
                #pragma unroll
                for (int i = 0; i < 4; ++i) acc[rt][i] += (float)pw[rt][i];
            }
            accS = b1S;
            #pragma unroll
            for (int i = 0; i < 4; ++i) accS[i] += (float)pwS[i];
            __builtin_amdgcn_s_setprio(1);
            #pragma unroll
            for (int kst = 0; kst < 4; ++kst) {
                half8 wA = *(const half8*)(W1t + (fw0+ln)*128 + kst*32 + q*8);
                half8 wS = *(const half8*)(W1t + (128+ln)*128 + kst*32 + q*8);
                int kb = kst*4 + q;
                #pragma unroll
                for (int rt = 0; rt < 8; ++rt) {
                    int row = rt*16 + ln;                // row & 15 == ln
                    half8 bf = *(const half8*)(cmx + row*128 + ((kb ^ ln)*8));
                    acc[rt] = MFMA(wA, bf, acc[rt]);
                    if (rt == w) accS = MFMA(wS, bf, accS);
                }
            }
            __builtin_amdgcn_s_setprio(0);
        }
        // [A2] removed: h1 writes target hB, disjoint from cmx reads.
        #pragma unroll
        for (int rt = 0; rt < 8; ++rt) {             // relu -> h1 over hB
            int row = rt*16 + ln;
            *(half4*)(hB + row*HSTR2 + fw0 + q*4) = relu_cvt4(acc[rt]);
        }
        *(half4*)(hB + (w*16 + ln)*HSTR2 + 128 + q*4) = relu_cvt4(accS);
        __syncthreads();                             // [B]

        // ---- L2': same balanced split, K=160 (zstrip covers cols 144..159) ----
        half4 h2[8], h2S;
        {
            const f32x4 b2w = *(const f32x4*)(b2p + fw0 + q*4);
            const f32x4 b2S = *(const f32x4*)(b2p + 128 + q*4);
            #pragma unroll
            for (int rt = 0; rt < 8; ++rt) acc[rt] = b2w;
            accS = b2S;
            __builtin_amdgcn_s_setprio(1);
            #pragma unroll
            for (int kst = 0; kst < 5; ++kst) {
                half8 wA = *(const half8*)(W2t + (fw0+ln)*160 + kst*32 + q*8);
                half8 wS = *(const half8*)(W2t + (128+ln)*160 + kst*32 + q*8);
                #pragma unroll
                for (int rt = 0; rt < 8; ++rt) {
                    int row = rt*16 + ln;
                    half8 bf = (kst < 4)
                        ? *(const half8*)(hB + row*HSTR2 + kst*32 + q*8)
                        : ((q < 2) ? *(const half8*)(hB + row*HSTR2 + 128 + q*8)
                                   : *(const half8*)zstrip);
                    acc[rt] = MFMA(wA, bf, acc[rt]);
                    if (rt == w) accS = MFMA(wS, bf, accS);
                }
            }
            __builtin_amdgcn_s_setprio(0);
            #pragma unroll
            for (int rt = 0; rt < 8; ++rt) h2[rt] = relu_cvt4(acc[rt]);
            h2S = relu_cvt4(accS);
        }
        __syncthreads();                             // [C] all h1 reads done
        #pragma unroll
        for (int rt = 0; rt < 8; ++rt) {
            int row = rt*16 + ln;
            *(half4*)(hB + row*HSTR2 + fw0 + q*4) = h2[rt];
        }
        *(half4*)(hB + (w*16 + ln)*HSTR2 + 128 + q*4) = h2S;
        __syncthreads();                             // [D]

        // ---- L3': z3^T = W3^T @ h2^T (4 o-tiles x 2 row-halves, balanced) ----
        {
            const f32x4 bz3 = *(const f32x4*)(b3 + og*16 + q*4);
            f32x4 z[4];
            #pragma unroll
            for (int rj = 0; rj < 4; ++rj) z[rj] = bz3;
            __builtin_amdgcn_s_setprio(1);
            #pragma unroll
            for (int kst = 0; kst < 5; ++kst) {
                half8 wO = *(const half8*)(W3t + (og*16+ln)*160 + kst*32 + q*8);
                #pragma unroll
                for (int rj = 0; rj < 4; ++rj) {
                    int row = (rg3*4 + rj)*16 + ln;
                    half8 bf = (kst < 4)
                        ? *(const half8*)(hB + row*HSTR2 + kst*32 + q*8)
                        : ((q < 2) ? *(const half8*)(hB + row*HSTR2 + 128 + q*8)
                                   : *(const half8*)zstrip);
                    z[rj] = MFMA(wO, bf, z[rj]);
                }
            }
            __builtin_amdgcn_s_setprio(0);
            // rows encode (j = rg3*2 + (rj>>1), b = (rj&1)*16 + ln); clamped
            // rows duplicate (s=127, same b) -> merge all unconditionally
            #pragma unroll
            for (int i = 0; i < 4; ++i) {
                rz0[i] = fmaxf(rz0[i], fmaxf(z[0][i], z[2][i]));
                rz1[i] = fmaxf(rz1[i], fmaxf(z[1][i], z[3][i]));
            }
        }
        // [E] removed: next item's staging writes cmx; L3 reads hB (disjoint).
    }

    // ---- final flush ----
    {
        if (rg3 == 1) {
            *(f32x4*)(scr + (og*64 + lane)*8)     = rz0;
            *(f32x4*)(scr + (og*64 + lane)*8 + 4) = rz1;
        }
        __syncthreads();
        if (rg3 == 0) {
            f32x4 p0 = *(const f32x4*)(scr + (og*64 + lane)*8);
            f32x4 p1 = *(const f32x4*)(scr + (og*64 + lane)*8 + 4);
            #pragma unroll
            for (int i = 0; i < 4; ++i) {
                rz0[i] = fmaxf(rz0[i], p0[i]);
                rz1[i] = fmaxf(rz1[i], p1[i]);
            }
            int k = bid - bid_of(2*(cur_t >> 2)*(65 - (cur_t >> 2))
                                 + (cur_t - 4*(cur_t >> 2))*(32 - (cur_t >> 2)));
            _Float16* sp = slots + ((size_t)cur_t*KSLOT + k)*2048;
            int o = og*16 + q*4;
            half4 z0 = cvt4(rz0), z1 = cvt4(rz1);
            __builtin_nontemporal_store(z0, (half4*)(sp + ln*64 + o));
            __builtin_nontemporal_store(z1, (half4*)(sp + (16+ln)*64 + o));
        }
    }
}

extern "C" void kernel_launch(void* const* d_in, const int* in_sizes, int n_in,
                              void* d_out, int out_size, void* d_ws, size_t ws_size,
                              hipStream_t stream) {
    const float* P  = (const float*)d_in[0];
    const float* W1 = (const float*)d_in[1];
    const float* b1 = (const float*)d_in[2];
    const float* W2 = (const float*)d_in[3];
    const float* b2 = (const float*)d_in[4];
    const float* W3 = (const float*)d_in[5];
    const float* b3 = (const float*)d_in[6];

    tll_prep<<<240, 256, 0, stream>>>(P, W1, b1, W2, b2, W3, (char*)d_ws);

    tll_main<<<NBLK, 512, 0, stream>>>(b3, (char*)d_ws);

    tll_finalize<<<128, 512, 0, stream>>>((const char*)d_ws, (float*)d_out);
}